// Round 7
// baseline (274.139 us; speedup 1.0000x reference)
//
#include <hip/hip_runtime.h>
#include <stdint.h>

#define BATCH   32
#define ROWS    4096
#define COLS    256
#define COL_IDX 5

typedef unsigned long long u64;
typedef unsigned int       u32;
typedef float f32x4 __attribute__((ext_vector_type(4)));   // native vec for
                                                           // nontemporal builtin

// ---------------------------------------------------------------------------
// Kernel 1: extract column COL_IDX, pack into order-preserving u64 keys.
//   hi 32 = ~(order_preserving_uint(f))  -> ascending u64 == descending float
//   lo 32 = row index                    -> distinct keys, stable tie-break
// ---------------------------------------------------------------------------
__global__ __launch_bounds__(256)
void extract_keys_kernel(const float* __restrict__ x, u64* __restrict__ keys) {
    const int i = blockIdx.x * 256 + threadIdx.x;      // 0 .. BATCH*ROWS-1
    u32 u = __float_as_uint(x[(size_t)i * COLS + COL_IDX]);
    u = (u >> 31) ? ~u : (u | 0x80000000u);            // order-preserving map
    u = ~u;                                            // descending
    keys[i] = ((u64)u << 32) | (u32)(i & (ROWS - 1));
}

// ---------------------------------------------------------------------------
// Kernel 2: ballot-rank + inverse-permutation store.
// Block owns 64 consecutive rows; each of 4 waves holds a 1024-key quarter
// in registers and counts keys < key_m via v_cmp_lt_u64 -> ballot ->
// s_bcnt1 (SALU pipe). Ranks within a batch are a true permutation (keys
// embed the row index -> all distinct).
// R5 LESSON: the scattered side of the permutation copy is the wall, and
// scattered WRITES are the worst direction. So this kernel emits the
// INVERSE permutation (srcg[output_row] = source_row, scattered 4 B
// stores, 512 KB total) so the big copy can run in gather form.
// ---------------------------------------------------------------------------
__global__ __launch_bounds__(256)
void rank_invert_kernel(const u64* __restrict__ keys, u32* __restrict__ srcg) {
    __shared__ int part[4][64];
    const int w    = (int)threadIdx.x >> 6;     // wave in block (0..3)
    const int lane = (int)threadIdx.x & 63;
    const int b    = blockIdx.x >> 6;           // 64 blocks per batch
    const int r0   = (blockIdx.x & 63) << 6;    // block's first row
    const u64* __restrict__ kb = keys + (size_t)b * ROWS;

    const int jbeg = w * (ROWS / 4);
    u64 kv[16];
    #pragma unroll
    for (int t = 0; t < 16; ++t)
        kv[t] = kb[jbeg + t * 64 + lane];
    const u64 my = kb[r0 + lane];

    const u32 my_lo = (u32)my, my_hi = (u32)(my >> 32);
    int vrank = 0;
    #pragma unroll 2
    for (int m = 0; m < 64; ++m) {
        const u32 klo = (u32)__builtin_amdgcn_readlane((int)my_lo, m);
        const u32 khi = (u32)__builtin_amdgcn_readlane((int)my_hi, m);
        const u64 mym = ((u64)khi << 32) | klo;
        int rank_m = 0;
        #pragma unroll
        for (int t = 0; t < 16; ++t)
            rank_m += (int)__popcll(__ballot(kv[t] < mym));
        vrank = (lane == m) ? rank_m : vrank;   // uniform rank_m -> lane m
    }

    part[w][lane] = vrank;
    __syncthreads();
    if (w == 0) {
        const int total = part[0][lane] + part[1][lane]
                        + part[2][lane] + part[3][lane];
        // inverse perm: output row (b*ROWS + total) comes from source row
        srcg[(size_t)b * ROWS + total] = (u32)(b * ROWS + r0 + lane);
    }
}

// ---------------------------------------------------------------------------
// Kernel 3: gather copy. Block owns 64 consecutive OUTPUT rows (4 waves x
// 16). Reads are the random side (1 KB each, absorbed by HBM read
// pipelining + L2/L3); writes are a 16 KB contiguous in-order stream per
// wave, stored NONTEMPORAL so the streaming output doesn't evict the
// cache lines serving the random reads. ~24 VGPR, no LDS, no barrier ->
// full occupancy.
// ---------------------------------------------------------------------------
__global__ __launch_bounds__(256)
void gather_copy_kernel(const float* __restrict__ x,
                        const u32* __restrict__ srcg,
                        float* __restrict__ out) {
    const int w    = (int)threadIdx.x >> 6;
    const int lane = (int)threadIdx.x & 63;
    const int or0  = blockIdx.x * 64 + w * 16;  // wave's first output row
    const f32x4* __restrict__ src = (const f32x4*)x;
    f32x4* __restrict__ o = (f32x4*)out;

    // preload the wave's 16 source indices (one coalesced dword load)
    const u32 sidx = srcg[or0 + (lane & 15)];

    #pragma unroll
    for (int t = 0; t < 16; ++t) {
        const u32 s = (u32)__builtin_amdgcn_readlane((int)sidx, t); // uniform
        const f32x4 v = src[(size_t)s * 64 + lane];                 // random 1 KB
        __builtin_nontemporal_store(v, &o[(size_t)(or0 + t) * 64 + lane]);
    }
}

extern "C" void kernel_launch(void* const* d_in, const int* in_sizes, int n_in,
                              void* d_out, int out_size, void* d_ws, size_t ws_size,
                              hipStream_t stream) {
    const float* x   = (const float*)d_in[0];
    float*       out = (float*)d_out;
    u64*         keys = (u64*)d_ws;                                   // 1 MB
    u32*         srcg = (u32*)((char*)d_ws + (size_t)BATCH * ROWS * 8); // +512 KB

    extract_keys_kernel<<<(BATCH * ROWS) / 256, 256, 0, stream>>>(x, keys);
    rank_invert_kernel<<<BATCH * 64, 256, 0, stream>>>(keys, srcg);
    gather_copy_kernel<<<(BATCH * ROWS) / 64, 256, 0, stream>>>(x, srcg, out);
}

// Round 8
// 256.907 us; speedup vs baseline: 1.0671x; 1.0671x over previous
//
#include <hip/hip_runtime.h>
#include <stdint.h>

#define BATCH   32
#define ROWS    4096
#define COLS    256
#define COL_IDX 5

typedef unsigned long long u64;
typedef unsigned int       u32;
typedef float f32x4 __attribute__((ext_vector_type(4)));   // native vec for
                                                           // nontemporal builtin

// ---------------------------------------------------------------------------
// Kernel 1: extract column COL_IDX, pack into order-preserving u64 keys.
//   hi 32 = ~(order_preserving_uint(f))  -> ascending u64 == descending float
//   lo 32 = row index                    -> distinct keys, stable tie-break
// ---------------------------------------------------------------------------
__global__ __launch_bounds__(256)
void extract_keys_kernel(const float* __restrict__ x, u64* __restrict__ keys) {
    const int i = blockIdx.x * 256 + threadIdx.x;      // 0 .. BATCH*ROWS-1
    u32 u = __float_as_uint(x[(size_t)i * COLS + COL_IDX]);
    u = (u >> 31) ? ~u : (u | 0x80000000u);            // order-preserving map
    u = ~u;                                            // descending
    keys[i] = ((u64)u << 32) | (u32)(i & (ROWS - 1));
}

// ---------------------------------------------------------------------------
// Kernel 2: fused ballot-rank + row copy (R3 champion structure; splits in
// R5/R7 were 27-31 us slower — fused overlaps rank VALU with copy latency
// across blocks).
// R8 changes:
//  (a) XCD pinning: b = blockIdx & 31 -> all 64 blocks of a batch have
//      blockIdx = b (mod 32), so the round-robin dispatcher puts the whole
//      batch on XCD b%8. Write footprint per XCD-L2 shrinks from all 32
//      batches to ~2 live batches; the batch's 32 KB key array lives in ONE
//      L2 instead of 8 copies.
//  (b) Copy MLP: batch 8 row-loads before 8 stores (8 KiB in flight/wave
//      vs 4 KiB with the old unroll-4 load->store pairs). v[8] = 32 VGPR,
//      loaded AFTER the rank loop so kv[16] is dead (avoids R2 spill trap).
//  (c) Nontemporal scattered stores: stream writes past L2 so it keeps
//      serving the read side.
// ---------------------------------------------------------------------------
__global__ __launch_bounds__(256, 4)
void rank_copy_kernel(const float* __restrict__ x,
                      const u64* __restrict__ keys,
                      float* __restrict__ out) {
    __shared__ int part[4][64];
    const int w    = (int)threadIdx.x >> 6;     // wave in block (0..3)
    const int lane = (int)threadIdx.x & 63;
    const int b    = blockIdx.x & 31;           // batch -> fixed XCD (b%8)
    const int r0   = (blockIdx.x >> 5) << 6;    // block's first row
    const u64* __restrict__ kb = keys + (size_t)b * ROWS;

    // ---- this wave's quarter of the key array (32 VGPRs) ----
    const int jbeg = w * (ROWS / 4);
    u64 kv[16];
    #pragma unroll
    for (int t = 0; t < 16; ++t)
        kv[t] = kb[jbeg + t * 64 + lane];
    const u64 my = kb[r0 + lane];

    // ---- ballot rank: broadcast row-key m, compare whole quarter ----
    const u32 my_lo = (u32)my, my_hi = (u32)(my >> 32);
    int vrank = 0;
    #pragma unroll 2
    for (int m = 0; m < 64; ++m) {
        const u32 klo = (u32)__builtin_amdgcn_readlane((int)my_lo, m);
        const u32 khi = (u32)__builtin_amdgcn_readlane((int)my_hi, m);
        const u64 mym = ((u64)khi << 32) | klo;
        int rank_m = 0;
        #pragma unroll
        for (int t = 0; t < 16; ++t)
            rank_m += (int)__popcll(__ballot(kv[t] < mym));
        vrank = (lane == m) ? rank_m : vrank;   // uniform rank_m -> lane m
    }

    part[w][lane] = vrank;
    __syncthreads();
    const int total = part[0][lane] + part[1][lane]
                    + part[2][lane] + part[3][lane];

    // ---- copy 64 rows; wave w handles rows [w*16, w*16+16).
    //      Two half-batches of 8: issue 8 loads, then 8 nt stores. ----
    const f32x4* __restrict__ src  =
        (const f32x4*)(x + ((size_t)b * ROWS + r0) * COLS);
    f32x4* __restrict__ outb = (f32x4*)(out + (size_t)b * ROWS * COLS);
    #pragma unroll
    for (int h = 0; h < 2; ++h) {
        f32x4 v[8];
        int   d8[8];
        #pragma unroll
        for (int t = 0; t < 8; ++t) {
            const int l = w * 16 + h * 8 + t;
            d8[t] = __builtin_amdgcn_readlane(total, l);   // uniform (SGPR)
            v[t]  = src[(size_t)l * 64 + lane];            // 8 KiB in flight
        }
        #pragma unroll
        for (int t = 0; t < 8; ++t)
            __builtin_nontemporal_store(v[t],
                &outb[(size_t)d8[t] * 64 + lane]);
    }
}

extern "C" void kernel_launch(void* const* d_in, const int* in_sizes, int n_in,
                              void* d_out, int out_size, void* d_ws, size_t ws_size,
                              hipStream_t stream) {
    const float* x   = (const float*)d_in[0];
    float*       out = (float*)d_out;
    u64*         keys = (u64*)d_ws;            // BATCH*ROWS*8 = 1 MB scratch

    extract_keys_kernel<<<(BATCH * ROWS) / 256, 256, 0, stream>>>(x, keys);
    rank_copy_kernel<<<BATCH * 64, 256, 0, stream>>>(x, keys, out);
}